// Round 1
// baseline (2456.170 us; speedup 1.0000x reference)
//
#include <hip/hip_runtime.h>

#define C_ 512
#define L_ 8192
#define BATCH 8
#define KW 3
#define WN (C_*C_*KW)   // 786432 elements per weight tensor
#define BM 128
#define BN 64
#define BK 32
#define LDSS 40         // padded LDS row stride (bf16 elems): bank step 20 -> ~conflict-free
#define NCOLS_MAX 74    // BN + 2*dil_max (dil=5)

typedef __bf16 v8bf __attribute__((ext_vector_type(8)));
typedef float v4f __attribute__((ext_vector_type(4)));
typedef unsigned short u16x8_t __attribute__((ext_vector_type(8)));

__device__ __forceinline__ unsigned short f2bf(float f) {
    union { float f; unsigned u; } c; c.f = f;
    unsigned r = c.u + 0x7fffu + ((c.u >> 16) & 1u);   // RNE
    return (unsigned short)(r >> 16);
}

__device__ __forceinline__ const float* pick6(int z, const float* a, const float* b,
                                              const float* c, const float* d,
                                              const float* e, const float* f) {
    switch (z) { case 0: return a; case 1: return b; case 2: return c;
                 case 3: return d; case 4: return e; default: return f; }
}

// ---- per-tensor sum(|w|) -> sums[z] (sums must be zeroed first) ----
__global__ void abssum_kernel(const float* w0, const float* w1, const float* w2,
                              const float* w3, const float* w4, const float* w5,
                              float* sums) {
    const float* w = pick6(blockIdx.z, w0, w1, w2, w3, w4, w5);
    const float4* w4p = (const float4*)w;
    float s = 0.f;
    for (int j = blockIdx.x * blockDim.x + threadIdx.x; j < WN / 4;
         j += gridDim.x * blockDim.x) {
        float4 v = w4p[j];
        s += fabsf(v.x) + fabsf(v.y) + fabsf(v.z) + fabsf(v.w);
    }
    __shared__ float red[256];
    red[threadIdx.x] = s;
    __syncthreads();
    for (int off = 128; off > 0; off >>= 1) {
        if ((int)threadIdx.x < off) red[threadIdx.x] += red[threadIdx.x + off];
        __syncthreads();
    }
    if (threadIdx.x == 0) atomicAdd(&sums[blockIdx.z], red[0]);
}

// ---- ternary quantize + transpose [O][I][K] fp32 -> [K][O][I] bf16 ----
__global__ void quantize_kernel(const float* w0, const float* w1, const float* w2,
                                const float* w3, const float* w4, const float* w5,
                                const float* sums, unsigned short* out) {
    int z = blockIdx.z;
    const float* w = pick6(z, w0, w1, w2, w3, w4, w5);
    float scl = sums[z] * (1.0f / (float)WN) + 1e-5f;
    int e = blockIdx.x * 256 + threadIdx.x;
    if (e >= WN) return;
    int k = e / (C_ * C_);
    int rem = e - k * (C_ * C_);
    int o = rem >> 9;          // /512
    int i = rem & (C_ - 1);
    float v = w[((size_t)o * C_ + i) * KW + k];
    float q = rintf(v / scl);  // rintf = round-half-even, matches jnp.round
    q = fminf(1.f, fmaxf(-1.f, q));
    out[(size_t)z * WN + e] = f2bf(q);  // exact: {-1,0,+1}
}

// ---- conv as 3 shifted GEMMs, bf16 MFMA 16x16x32 ----
// IN_F32: 1 -> xin is fp32 (convert during staging); 0 -> xin is bf16 bits
// MODE:   0 -> out = bf16( leaky(scale*acc + bias) )   (conv1 -> h buffer)
//         1 -> out = fp32( xres + scale*acc + bias )   (conv2 -> residual)
template<int IN_F32, int MODE>
__global__ __launch_bounds__(256)
void conv_kernel(const void* __restrict__ xin, const unsigned short* __restrict__ wq,
                 const float* __restrict__ sums, int tidx, const float* __restrict__ bias,
                 const float* __restrict__ xres, void* __restrict__ out, int dil) {
    __shared__ __align__(16) unsigned short sW[KW][BM][LDSS];   // 30720 B
    __shared__ __align__(16) unsigned short sX[NCOLS_MAX][LDSS]; // 5920 B

    const int tid  = threadIdx.x;
    const int lane = tid & 63;
    const int wid  = tid >> 6;
    const int wm = wid >> 1, wn = wid & 1;   // 2x2 waves -> 128x64 block tile
    const int l15 = lane & 15, quad = lane >> 4;
    const int l0 = blockIdx.x * BN;
    const int o0 = blockIdx.y * BM;
    const int bb = blockIdx.z;
    const int ncols = BN + 2 * dil;

    v4f acc[4][2] = {};

    for (int kc = 0; kc < C_ / BK; ++kc) {
        __syncthreads();
        // stage W: 3 taps x 128 rows x 32 cols bf16, 16B vector loads
        #pragma unroll
        for (int jj = 0; jj < 6; ++jj) {
            int e = tid + jj * 256;          // 0..1535
            int t = e >> 9;
            int rem = e & 511;
            int row = rem >> 2;
            int seg = rem & 3;
            const u16x8_t* src = (const u16x8_t*)(wq + (size_t)t * (C_ * C_) +
                                                  (size_t)(o0 + row) * C_ + kc * BK + seg * 8);
            *(u16x8_t*)&sW[t][row][seg * 8] = *src;
        }
        // stage X transposed: sX[col][i_local], halo of dil on both sides, zero-pad OOB
        int nelem = ncols * BK;
        for (int e = tid; e < nelem; e += 256) {
            int col = e % ncols;
            int row = e / ncols;
            int gl = l0 - dil + col;
            unsigned short bits = 0;
            if (gl >= 0 && gl < L_) {
                size_t off = ((size_t)bb * C_ + (kc * BK + row)) * (size_t)L_ + gl;
                if (IN_F32) bits = f2bf(((const float*)xin)[off]);
                else        bits = ((const unsigned short*)xin)[off];
            }
            sX[col][row] = bits;
        }
        __syncthreads();

        #pragma unroll
        for (int t = 0; t < KW; ++t) {
            v8bf af[4], bf[2];
            #pragma unroll
            for (int mi = 0; mi < 4; ++mi)
                af[mi] = __builtin_bit_cast(v8bf,
                    *(const u16x8_t*)&sW[t][wm * 64 + mi * 16 + l15][quad * 8]);
            #pragma unroll
            for (int ni = 0; ni < 2; ++ni)
                bf[ni] = __builtin_bit_cast(v8bf,
                    *(const u16x8_t*)&sX[wn * 32 + ni * 16 + l15 + t * dil][quad * 8]);
            #pragma unroll
            for (int mi = 0; mi < 4; ++mi)
                #pragma unroll
                for (int ni = 0; ni < 2; ++ni)
                    acc[mi][ni] = __builtin_amdgcn_mfma_f32_16x16x32_bf16(
                        af[mi], bf[ni], acc[mi][ni], 0, 0, 0);
        }
    }

    float scl = sums[tidx] * (1.0f / (float)WN) + 1e-5f;
    #pragma unroll
    for (int mi = 0; mi < 4; ++mi) {
        int mbase = o0 + wm * 64 + mi * 16 + quad * 4;
        #pragma unroll
        for (int ni = 0; ni < 2; ++ni) {
            int n = l0 + wn * 32 + ni * 16 + l15;
            #pragma unroll
            for (int r = 0; r < 4; ++r) {
                int m = mbase + r;
                float v = acc[mi][ni][r] * scl + bias[m];
                size_t off = ((size_t)bb * C_ + m) * (size_t)L_ + n;
                if (MODE == 0) {
                    v = (v >= 0.f) ? v : 0.1f * v;
                    ((unsigned short*)out)[off] = f2bf(v);
                } else {
                    ((float*)out)[off] = xres[off] + v;
                }
            }
        }
    }
}

extern "C" void kernel_launch(void* const* d_in, const int* in_sizes, int n_in,
                              void* d_out, int out_size, void* d_ws, size_t ws_size,
                              hipStream_t stream) {
    const float* x = (const float*)d_in[0];
    const float* w[6];
    const float* bs[6];
    for (int i = 0; i < 6; ++i) {
        w[i]  = (const float*)d_in[1 + 2 * i];
        bs[i] = (const float*)d_in[2 + 2 * i];
    }
    float* sums = (float*)d_ws;                                          // 6 floats
    unsigned short* wqb = (unsigned short*)((char*)d_ws + 64);           // 6 * 1.5 MB ternary bf16
    unsigned short* hb  = (unsigned short*)((char*)d_ws + 64 + (size_t)6 * WN * 2);  // 67 MB h bf16
    float* outf = (float*)d_out;

    hipMemsetAsync(d_ws, 0, 64, stream);
    abssum_kernel<<<dim3(256, 1, 6), 256, 0, stream>>>(w[0], w[1], w[2], w[3], w[4], w[5], sums);
    quantize_kernel<<<dim3(WN / 256, 1, 6), 256, 0, stream>>>(w[0], w[1], w[2], w[3], w[4], w[5],
                                                              sums, wqb);

    dim3 grid(L_ / BN, C_ / BM, BATCH);
    const int dils[3] = {1, 3, 5};
    for (int i = 0; i < 3; ++i) {
        const float* xin_f = (i == 0) ? x : outf;
        // conv1 (dilated) -> h (bf16), fused leaky
        conv_kernel<1, 0><<<grid, 256, 0, stream>>>(
            (const void*)xin_f, wqb + (size_t)(2 * i) * WN, sums, 2 * i, bs[2 * i],
            nullptr, (void*)hb, dils[i]);
        // conv2 (dense) -> d_out (fp32), fused residual add (in-place safe: same-element RMW)
        conv_kernel<0, 1><<<grid, 256, 0, stream>>>(
            (const void*)hb, wqb + (size_t)(2 * i + 1) * WN, sums, 2 * i + 1, bs[2 * i + 1],
            xin_f, (void*)outf, 1);
    }
}

// Round 2
// 1253.523 us; speedup vs baseline: 1.9594x; 1.9594x over previous
//
#include <hip/hip_runtime.h>

#define C_ 512
#define L_ 8192
#define BATCH 8
#define KW 3
#define WN (C_*C_*KW)   // 786432 elements per weight tensor
#define BM 128
#define BN 128
#define BK 32
#define LDSS 40         // padded LDS stride (bf16 elems): 80 B = 16B-aligned, bank step 20 -> ~2-way on b128

typedef __bf16 v8bf __attribute__((ext_vector_type(8)));
typedef float v4f __attribute__((ext_vector_type(4)));
typedef unsigned short u16x8_t __attribute__((ext_vector_type(8)));
typedef unsigned short u16x4_t __attribute__((ext_vector_type(4)));

__device__ __forceinline__ unsigned short f2bf(float f) {
    union { float f; unsigned u; } c; c.f = f;
    unsigned r = c.u + 0x7fffu + ((c.u >> 16) & 1u);   // RNE
    return (unsigned short)(r >> 16);
}
__device__ __forceinline__ float bf2f(unsigned short b) {
    union { unsigned u; float f; } c; c.u = ((unsigned)b) << 16;
    return c.f;
}

__device__ __forceinline__ const float* pick6(int z, const float* a, const float* b,
                                              const float* c, const float* d,
                                              const float* e, const float* f) {
    switch (z) { case 0: return a; case 1: return b; case 2: return c;
                 case 3: return d; case 4: return e; default: return f; }
}

// ---- per-tensor sum(|w|) -> sums[z] (sums zeroed first) ----
__global__ void abssum_kernel(const float* w0, const float* w1, const float* w2,
                              const float* w3, const float* w4, const float* w5,
                              float* sums) {
    const float* w = pick6(blockIdx.z, w0, w1, w2, w3, w4, w5);
    const float4* w4p = (const float4*)w;
    float s = 0.f;
    for (int j = blockIdx.x * blockDim.x + threadIdx.x; j < WN / 4;
         j += gridDim.x * blockDim.x) {
        float4 v = w4p[j];
        s += fabsf(v.x) + fabsf(v.y) + fabsf(v.z) + fabsf(v.w);
    }
    __shared__ float red[256];
    red[threadIdx.x] = s;
    __syncthreads();
    for (int off = 128; off > 0; off >>= 1) {
        if ((int)threadIdx.x < off) red[threadIdx.x] += red[threadIdx.x + off];
        __syncthreads();
    }
    if (threadIdx.x == 0) atomicAdd(&sums[blockIdx.z], red[0]);
}

// ---- ternary quantize + transpose [O][I][K] fp32 -> [K][O][I] bf16 ----
__global__ void quantize_kernel(const float* w0, const float* w1, const float* w2,
                                const float* w3, const float* w4, const float* w5,
                                const float* sums, unsigned short* out) {
    int z = blockIdx.z;
    const float* w = pick6(z, w0, w1, w2, w3, w4, w5);
    float scl = sums[z] * (1.0f / (float)WN) + 1e-5f;
    int e = blockIdx.x * 256 + threadIdx.x;
    if (e >= WN) return;
    int k = e / (C_ * C_);
    int rem = e - k * (C_ * C_);
    int o = rem >> 9;
    int i = rem & (C_ - 1);
    float v = w[((size_t)o * C_ + i) * KW + k];
    float q = rintf(v / scl);
    q = fminf(1.f, fmaxf(-1.f, q));
    out[(size_t)z * WN + e] = f2bf(q);  // exact: {-1,0,+1}
}

// ---- x fp32 [b][c][l] -> xT bf16 chunked [b][c/32][l][c%32] ----
__global__ __launch_bounds__(256) void transpose_kernel(const float* __restrict__ x,
                                                        unsigned short* __restrict__ xT) {
    __shared__ __align__(16) unsigned short tl[128][40];
    int b = blockIdx.z, g = blockIdx.y, l0 = blockIdx.x * 128;
    #pragma unroll
    for (int i = 0; i < 4; ++i) {
        int idx = threadIdx.x + i * 256;     // 1024 float4s: 32 c x 32 l4
        int c = idx >> 5, lp = (idx & 31) * 4;
        float4 v = *(const float4*)&x[((size_t)b * C_ + g * 32 + c) * L_ + l0 + lp];
        tl[lp][c] = f2bf(v.x); tl[lp+1][c] = f2bf(v.y);
        tl[lp+2][c] = f2bf(v.z); tl[lp+3][c] = f2bf(v.w);
    }
    __syncthreads();
    #pragma unroll
    for (int i = 0; i < 2; ++i) {
        int ch = threadIdx.x + i * 256;      // 512 chunks: 128 l x 4 segs
        int l = ch >> 2, seg = ch & 3;
        *(u16x8_t*)(xT + (((size_t)b * 16 + g) * L_ + l0 + l) * 32 + seg * 8) =
            *(const u16x8_t*)&tl[l][seg * 8];
    }
}

// ---- conv as 3 shifted GEMMs, bf16 MFMA 16x16x32, 128x128 block tile ----
// SRC 0: xin = bf16 chunked [b][g][l][32]; SRC 1: xin = fp32 [b][c][l]
// RES 0: out = hT bf16 chunked, fused leaky
// RES 1: resbuf = xT bf16 chunked (RMW residual), out = d_out fp32 (write)
// RES 2: resbuf = d_out fp32 [b][c][l] (RMW residual)
template<int SRC, int DIL, int RES>
__global__ __launch_bounds__(256)
void conv_kernel(const void* __restrict__ xin, const unsigned short* __restrict__ wq,
                 const float* __restrict__ sums, int tidx, const float* __restrict__ bias,
                 void* __restrict__ resbuf, void* __restrict__ out) {
    constexpr int NCOLS = BN + 2 * DIL;
    __shared__ __align__(16) unsigned short sW[KW][BM][LDSS];   // 30720 B
    __shared__ __align__(16) unsigned short sX[NCOLS][LDSS];    // <= 11040 B

    const int tid  = threadIdx.x;
    const int lane = tid & 63;
    const int wid  = tid >> 6;
    const int wm = wid >> 1, wn = wid & 1;       // 2x2 waves, each 64x64
    const int l15 = lane & 15, quad = lane >> 4;
    const int l0 = blockIdx.x * BN;
    const int o0 = blockIdx.y * BM;
    const int bb = blockIdx.z;

    v4f acc[4][4] = {};

    for (int kc = 0; kc < C_ / BK; ++kc) {
        __syncthreads();
        // stage W: 3 taps x 128 rows x 32 cols, b128 in/out
        #pragma unroll
        for (int jj = 0; jj < 6; ++jj) {
            int e = tid + jj * 256;          // 0..1535
            int t = e >> 9;
            int rem = e & 511;
            int row = rem >> 2;
            int seg = rem & 3;
            u16x8_t v = *(const u16x8_t*)(wq + (size_t)t * (C_ * C_) +
                                          (size_t)(o0 + row) * C_ + kc * BK + seg * 8);
            *(u16x8_t*)&sW[t][row][seg * 8] = v;
        }
        // stage X
        if (SRC == 0) {
            constexpr int NCH = NCOLS * 4;   // 16B chunks
            for (int e = tid; e < NCH; e += 256) {
                int col = e >> 2, seg = e & 3;
                int gl = l0 - DIL + col;
                u16x8_t v = {0, 0, 0, 0, 0, 0, 0, 0};
                if (gl >= 0 && gl < L_)
                    v = *(const u16x8_t*)((const unsigned short*)xin +
                        (((size_t)bb * 16 + kc) * L_ + gl) * 32 + seg * 8);
                *(u16x8_t*)&sX[col][seg * 8] = v;
            }
        } else {
            constexpr int NE = NCOLS * BK;
            for (int e = tid; e < NE; e += 256) {
                int row = e / NCOLS;          // constexpr divisor -> magic mul
                int col = e - row * NCOLS;
                int gl = l0 - DIL + col;
                unsigned short bits = 0;
                if (gl >= 0 && gl < L_)
                    bits = f2bf(((const float*)xin)[((size_t)bb * C_ + kc * BK + row) * L_ + gl]);
                sX[col][row] = bits;
            }
        }
        __syncthreads();

        #pragma unroll
        for (int t = 0; t < KW; ++t) {
            v8bf af[4], bfr[4];
            #pragma unroll
            for (int mi = 0; mi < 4; ++mi)
                af[mi] = __builtin_bit_cast(v8bf,
                    *(const u16x8_t*)&sW[t][wm * 64 + mi * 16 + l15][quad * 8]);
            #pragma unroll
            for (int ni = 0; ni < 4; ++ni)
                bfr[ni] = __builtin_bit_cast(v8bf,
                    *(const u16x8_t*)&sX[wn * 64 + ni * 16 + l15 + t * DIL][quad * 8]);
            #pragma unroll
            for (int mi = 0; mi < 4; ++mi)
                #pragma unroll
                for (int ni = 0; ni < 4; ++ni)
                    acc[mi][ni] = __builtin_amdgcn_mfma_f32_16x16x32_bf16(
                        af[mi], bfr[ni], acc[mi][ni], 0, 0, 0);
        }
    }

    float scl = sums[tidx] * (1.0f / (float)WN) + 1e-5f;
    #pragma unroll
    for (int mi = 0; mi < 4; ++mi) {
        int mb = o0 + wm * 64 + mi * 16 + quad * 4;      // 4 consecutive o: mb..mb+3
        int g  = mb >> 5;
        int j  = mb & 31;                                 // (mi&1)*16 + quad*4
        #pragma unroll
        for (int ni = 0; ni < 4; ++ni) {
            int n = l0 + wn * 64 + ni * 16 + l15;
            if (RES == 0) {
                u16x4_t pk;
                #pragma unroll
                for (int r = 0; r < 4; ++r) {
                    float v = acc[mi][ni][r] * scl + bias[mb + r];
                    v = (v >= 0.f) ? v : 0.1f * v;
                    pk[r] = f2bf(v);
                }
                *(u16x4_t*)((unsigned short*)out +
                    (((size_t)bb * 16 + g) * L_ + n) * 32 + j) = pk;
            } else if (RES == 1) {
                unsigned short* xp = (unsigned short*)resbuf +
                    (((size_t)bb * 16 + g) * L_ + n) * 32 + j;
                u16x4_t old = *(const u16x4_t*)xp;
                u16x4_t nw;
                #pragma unroll
                for (int r = 0; r < 4; ++r) {
                    float v = bf2f(old[r]) + acc[mi][ni][r] * scl + bias[mb + r];
                    nw[r] = f2bf(v);
                    ((float*)out)[((size_t)bb * C_ + mb + r) * L_ + n] = v;
                }
                *(u16x4_t*)xp = nw;
            } else {
                #pragma unroll
                for (int r = 0; r < 4; ++r) {
                    float* p = (float*)resbuf + ((size_t)bb * C_ + mb + r) * L_ + n;
                    *p = *p + acc[mi][ni][r] * scl + bias[mb + r];
                }
            }
        }
    }
}

extern "C" void kernel_launch(void* const* d_in, const int* in_sizes, int n_in,
                              void* d_out, int out_size, void* d_ws, size_t ws_size,
                              hipStream_t stream) {
    const float* x = (const float*)d_in[0];
    const float* w[6];
    const float* bs[6];
    for (int i = 0; i < 6; ++i) {
        w[i]  = (const float*)d_in[1 + 2 * i];
        bs[i] = (const float*)d_in[2 + 2 * i];
    }
    char* ws = (char*)d_ws;
    float* sums = (float*)ws;
    unsigned short* wqb = (unsigned short*)(ws + 64);
    const size_t HB = (size_t)BATCH * C_ * L_ * 2;              // 67108864 B
    const size_t need_fast = 64 + (size_t)6 * WN * 2 + 2 * HB;  // ~143.7 MB
    const bool fast = ws_size >= need_fast;
    unsigned short* xT = (unsigned short*)(ws + 64 + (size_t)6 * WN * 2);
    unsigned short* hT = fast ? (unsigned short*)((char*)xT + HB) : xT;
    float* outf = (float*)d_out;

    hipMemsetAsync(d_ws, 0, 64, stream);
    abssum_kernel<<<dim3(256, 1, 6), 256, 0, stream>>>(w[0], w[1], w[2], w[3], w[4], w[5], sums);
    quantize_kernel<<<dim3(WN / 256, 1, 6), 256, 0, stream>>>(w[0], w[1], w[2], w[3], w[4], w[5],
                                                              sums, wqb);
    if (fast) {
        transpose_kernel<<<dim3(L_ / 128, 16, BATCH), 256, 0, stream>>>(x, xT);
    } else {
        hipMemcpyAsync(d_out, x, (size_t)BATCH * C_ * L_ * 4, hipMemcpyDeviceToDevice, stream);
    }

    dim3 grid(L_ / BN, C_ / BM, BATCH);
    for (int i = 0; i < 3; ++i) {
        const unsigned short* wq1 = wqb + (size_t)(2 * i) * WN;
        const unsigned short* wq2 = wqb + (size_t)(2 * i + 1) * WN;
        if (fast) {
            if (i == 0)      conv_kernel<0, 1, 0><<<grid, 256, 0, stream>>>(xT, wq1, sums, 0, bs[0], nullptr, hT);
            else if (i == 1) conv_kernel<0, 3, 0><<<grid, 256, 0, stream>>>(xT, wq1, sums, 2, bs[2], nullptr, hT);
            else             conv_kernel<0, 5, 0><<<grid, 256, 0, stream>>>(xT, wq1, sums, 4, bs[4], nullptr, hT);
            conv_kernel<0, 1, 1><<<grid, 256, 0, stream>>>(hT, wq2, sums, 2 * i + 1, bs[2 * i + 1],
                                                           xT, outf);
        } else {
            if (i == 0)      conv_kernel<1, 1, 0><<<grid, 256, 0, stream>>>(outf, wq1, sums, 0, bs[0], nullptr, hT);
            else if (i == 1) conv_kernel<1, 3, 0><<<grid, 256, 0, stream>>>(outf, wq1, sums, 2, bs[2], nullptr, hT);
            else             conv_kernel<1, 5, 0><<<grid, 256, 0, stream>>>(outf, wq1, sums, 4, bs[4], nullptr, hT);
            conv_kernel<0, 1, 2><<<grid, 256, 0, stream>>>(hT, wq2, sums, 2 * i + 1, bs[2 * i + 1],
                                                           outf, nullptr);
        }
    }
}

// Round 3
// 849.758 us; speedup vs baseline: 2.8904x; 1.4752x over previous
//
#include <hip/hip_runtime.h>

#define C_ 512
#define L_ 8192
#define BATCH 8
#define KW 3
#define WN (C_*C_*KW)   // 786432 elements per weight tensor
#define BM 128
#define BN 128
#define BK 32
#define LDSS 40         // fallback kernel only

typedef __bf16 v8bf __attribute__((ext_vector_type(8)));
typedef float v4f __attribute__((ext_vector_type(4)));
typedef unsigned short u16x8_t __attribute__((ext_vector_type(8)));
typedef unsigned short u16x4_t __attribute__((ext_vector_type(4)));

__device__ __forceinline__ unsigned short f2bf(float f) {
    union { float f; unsigned u; } c; c.f = f;
    unsigned r = c.u + 0x7fffu + ((c.u >> 16) & 1u);   // RNE
    return (unsigned short)(r >> 16);
}
__device__ __forceinline__ float bf2f(unsigned short b) {
    union { unsigned u; float f; } c; c.u = ((unsigned)b) << 16;
    return c.f;
}

__device__ __forceinline__ void gl_lds16(const void* g, void* l) {
    // async 16B/lane global->LDS; LDS dst = wave-uniform base + lane*16
    __builtin_amdgcn_global_load_lds(
        (const __attribute__((address_space(1))) unsigned int*)g,
        (__attribute__((address_space(3))) unsigned int*)l, 16, 0, 0);
}

__device__ __forceinline__ const float* pick6(int z, const float* a, const float* b,
                                              const float* c, const float* d,
                                              const float* e, const float* f) {
    switch (z) { case 0: return a; case 1: return b; case 2: return c;
                 case 3: return d; case 4: return e; default: return f; }
}

// ---- per-tensor sum(|w|) -> sums[z] (sums zeroed first) ----
__global__ void abssum_kernel(const float* w0, const float* w1, const float* w2,
                              const float* w3, const float* w4, const float* w5,
                              float* sums) {
    const float* w = pick6(blockIdx.z, w0, w1, w2, w3, w4, w5);
    const float4* w4p = (const float4*)w;
    float s = 0.f;
    for (int j = blockIdx.x * blockDim.x + threadIdx.x; j < WN / 4;
         j += gridDim.x * blockDim.x) {
        float4 v = w4p[j];
        s += fabsf(v.x) + fabsf(v.y) + fabsf(v.z) + fabsf(v.w);
    }
    __shared__ float red[256];
    red[threadIdx.x] = s;
    __syncthreads();
    for (int off = 128; off > 0; off >>= 1) {
        if ((int)threadIdx.x < off) red[threadIdx.x] += red[threadIdx.x + off];
        __syncthreads();
    }
    if (threadIdx.x == 0) atomicAdd(&sums[blockIdx.z], red[0]);
}

// ---- ternary quantize + transpose [O][I][K] fp32 -> [K][O][I] bf16 ----
__global__ void quantize_kernel(const float* w0, const float* w1, const float* w2,
                                const float* w3, const float* w4, const float* w5,
                                const float* sums, unsigned short* out) {
    int z = blockIdx.z;
    const float* w = pick6(z, w0, w1, w2, w3, w4, w5);
    float scl = sums[z] * (1.0f / (float)WN) + 1e-5f;
    int e = blockIdx.x * 256 + threadIdx.x;
    if (e >= WN) return;
    int k = e / (C_ * C_);
    int rem = e - k * (C_ * C_);
    int o = rem >> 9;
    int i = rem & (C_ - 1);
    float v = w[((size_t)o * C_ + i) * KW + k];
    float q = rintf(v / scl);
    q = fminf(1.f, fmaxf(-1.f, q));
    out[(size_t)z * WN + e] = f2bf(q);  // exact: {-1,0,+1}
}

// ---- x fp32 [b][c][l] -> xT bf16 chunked [b][c/32][l][c%32] ----
__global__ __launch_bounds__(256) void transpose_kernel(const float* __restrict__ x,
                                                        unsigned short* __restrict__ xT) {
    __shared__ __align__(16) unsigned short tl[128][40];
    int b = blockIdx.z, g = blockIdx.y, l0 = blockIdx.x * 128;
    #pragma unroll
    for (int i = 0; i < 4; ++i) {
        int idx = threadIdx.x + i * 256;     // 1024 float4s: 32 c x 32 l4
        int c = idx >> 5, lp = (idx & 31) * 4;
        float4 v = *(const float4*)&x[((size_t)b * C_ + g * 32 + c) * L_ + l0 + lp];
        tl[lp][c] = f2bf(v.x); tl[lp+1][c] = f2bf(v.y);
        tl[lp+2][c] = f2bf(v.z); tl[lp+3][c] = f2bf(v.w);
    }
    __syncthreads();
    #pragma unroll
    for (int i = 0; i < 2; ++i) {
        int ch = threadIdx.x + i * 256;      // 512 chunks: 128 l x 4 segs
        int l = ch >> 2, seg = ch & 3;
        *(u16x8_t*)(xT + (((size_t)b * 16 + g) * L_ + l0 + l) * 32 + seg * 8) =
            *(const u16x8_t*)&tl[l][seg * 8];
    }
}

// ==== FAST conv: global_load_lds staging + XOR-swizzled LDS, 128x128 tile ====
// xin: bf16 chunked [b][g][l][32]
// RES 0: out = hT bf16 chunked, fused leaky
// RES 1: resbuf = xT bf16 chunked, RMW residual (no fp32 write)
// RES 3: resbuf = xT (read), out = d_out fp32 (write final)
template<int DIL, int RES>
__global__ __launch_bounds__(256)
void conv_fast(const unsigned short* __restrict__ xin, const unsigned short* __restrict__ wq,
               const float* __restrict__ sums, int tidx, const float* __restrict__ bias,
               void* __restrict__ resbuf, void* __restrict__ out) {
    // sW: 1536 chunks (3 taps x 128 rows x 4 segs) x 16B; seg swizzled by (row>>2)&3
    // sX: 576 chunks (144 cols x 4 segs) x 16B; seg swizzled by (col>>2)&3
    __shared__ __align__(16) unsigned short sW[1536 * 8];   // 24576 B
    __shared__ __align__(16) unsigned short sX[576 * 8];    //  9216 B

    const int tid  = threadIdx.x;
    const int lane = tid & 63;
    const int wid  = tid >> 6;
    const int wm = wid >> 1, wn = wid & 1;       // 2x2 waves, each 64x64
    const int l15 = lane & 15, quad = lane >> 4;
    const int l0 = blockIdx.x * BN;
    const int o0 = blockIdx.y * BM;
    const int bb = blockIdx.z;

    // --- staging precompute (element offsets; lane-dependent) ---
    int woffE[6];
    #pragma unroll
    for (int j = 0; j < 6; ++j) {
        int c = (wid * 6 + j) * 64 + lane;       // chunk index 0..1535
        int t = c >> 9, row = (c >> 2) & 127, s2 = c & 3;
        int seg = s2 ^ ((row >> 2) & 3);
        woffE[j] = t * (C_ * C_) + (o0 + row) * C_ + seg * 8;
    }
    const int nx = (wid == 0) ? 3 : 2;           // 9 X-instrs over 4 waves
    int xoffE[3];
    #pragma unroll
    for (int u = 0; u < 3; ++u) {
        int j = wid + 4 * u; if (j > 8) j = 8;
        int c = j * 64 + lane;                   // chunk index 0..575
        int col = c >> 2, s2 = c & 3;
        int seg = s2 ^ ((col >> 2) & 3);
        int gl = l0 - DIL + col;
        gl = min(max(gl, 0), L_ - 1);            // clamp; edge blocks re-zero OOB cols
        xoffE[u] = gl * 32 + seg * 8;
    }
    const int aswz = quad ^ ((l15 >> 2) & 3);
    const bool edge = (blockIdx.x == 0) || (blockIdx.x == gridDim.x - 1);

    v4f acc[4][4] = {};

    for (int kc = 0; kc < C_ / BK; ++kc) {
        __syncthreads();                          // all waves done reading prev tile
        const unsigned short* wbase = wq + kc * BK;
        #pragma unroll
        for (int j = 0; j < 6; ++j)
            gl_lds16(wbase + woffE[j], (char*)sW + (wid * 6 + j) * 1024);
        const unsigned short* xbase = xin + (size_t)(bb * 16 + kc) * (L_ * 32);
        #pragma unroll
        for (int u = 0; u < 3; ++u)
            if (u < nx)                           // wave-uniform predicate
                gl_lds16(xbase + xoffE[u], (char*)sX + (wid + 4 * u) * 1024);
        __syncthreads();                          // vmcnt(0) drain + barrier -> tile ready
        if (edge) {                               // zero OOB halo cols (block-uniform branch)
            if (tid < DIL * 4) {
                int col = ((blockIdx.x == 0) ? 0 : (BN + DIL)) + (tid >> 2);
                int s = tid & 3;
                u16x8_t z = {0, 0, 0, 0, 0, 0, 0, 0};
                *(u16x8_t*)((char*)sX + ((col * 4 + s) << 4)) = z;
            }
            __syncthreads();
        }

        #pragma unroll
        for (int t = 0; t < KW; ++t) {
            v8bf af[4], bfr[4];
            #pragma unroll
            for (int mi = 0; mi < 4; ++mi) {
                int arow = wm * 64 + mi * 16 + l15;
                af[mi] = __builtin_bit_cast(v8bf, *(const u16x8_t*)
                    ((const char*)sW + ((t * 512 + arow * 4 + aswz) << 4)));
            }
            #pragma unroll
            for (int ni = 0; ni < 4; ++ni) {
                int col = wn * 64 + ni * 16 + l15 + t * DIL;
                int bswz = quad ^ ((col >> 2) & 3);
                bfr[ni] = __builtin_bit_cast(v8bf, *(const u16x8_t*)
                    ((const char*)sX + ((col * 4 + bswz) << 4)));
            }
            #pragma unroll
            for (int mi = 0; mi < 4; ++mi)
                #pragma unroll
                for (int ni = 0; ni < 4; ++ni)
                    acc[mi][ni] = __builtin_amdgcn_mfma_f32_16x16x32_bf16(
                        af[mi], bfr[ni], acc[mi][ni], 0, 0, 0);
        }
    }

    float scl = sums[tidx] * (1.0f / (float)WN) + 1e-5f;
    #pragma unroll
    for (int mi = 0; mi < 4; ++mi) {
        int mb = o0 + wm * 64 + mi * 16 + quad * 4;      // 4 consecutive o
        int g  = mb >> 5;
        int j  = mb & 31;
        #pragma unroll
        for (int ni = 0; ni < 4; ++ni) {
            int n = l0 + wn * 64 + ni * 16 + l15;
            if (RES == 0) {
                u16x4_t pk;
                #pragma unroll
                for (int r = 0; r < 4; ++r) {
                    float v = acc[mi][ni][r] * scl + bias[mb + r];
                    v = (v >= 0.f) ? v : 0.1f * v;
                    pk[r] = f2bf(v);
                }
                *(u16x4_t*)((unsigned short*)out +
                    (((size_t)bb * 16 + g) * L_ + n) * 32 + j) = pk;
            } else if (RES == 1) {
                unsigned short* xp = (unsigned short*)resbuf +
                    (((size_t)bb * 16 + g) * L_ + n) * 32 + j;
                u16x4_t old = *(const u16x4_t*)xp;
                u16x4_t nw;
                #pragma unroll
                for (int r = 0; r < 4; ++r)
                    nw[r] = f2bf(bf2f(old[r]) + acc[mi][ni][r] * scl + bias[mb + r]);
                *(u16x4_t*)xp = nw;
            } else {  // RES == 3: final -> fp32 d_out
                const unsigned short* xp = (const unsigned short*)resbuf +
                    (((size_t)bb * 16 + g) * L_ + n) * 32 + j;
                u16x4_t old = *(const u16x4_t*)xp;
                #pragma unroll
                for (int r = 0; r < 4; ++r)
                    ((float*)out)[((size_t)bb * C_ + mb + r) * L_ + n] =
                        bf2f(old[r]) + acc[mi][ni][r] * scl + bias[mb + r];
            }
        }
    }
}

// ==== fallback conv (round-2 style; used only if ws too small) ====
template<int SRC, int DIL, int RES>
__global__ __launch_bounds__(256)
void conv_fb(const void* __restrict__ xin, const unsigned short* __restrict__ wq,
             const float* __restrict__ sums, int tidx, const float* __restrict__ bias,
             void* __restrict__ resbuf, void* __restrict__ out) {
    constexpr int NCOLS = BN + 2 * DIL;
    __shared__ __align__(16) unsigned short sW[KW][BM][LDSS];
    __shared__ __align__(16) unsigned short sX[NCOLS][LDSS];
    const int tid  = threadIdx.x;
    const int lane = tid & 63;
    const int wid  = tid >> 6;
    const int wm = wid >> 1, wn = wid & 1;
    const int l15 = lane & 15, quad = lane >> 4;
    const int l0 = blockIdx.x * BN;
    const int o0 = blockIdx.y * BM;
    const int bb = blockIdx.z;
    v4f acc[4][4] = {};
    for (int kc = 0; kc < C_ / BK; ++kc) {
        __syncthreads();
        #pragma unroll
        for (int jj = 0; jj < 6; ++jj) {
            int e = tid + jj * 256;
            int t = e >> 9, rem = e & 511, row = rem >> 2, seg = rem & 3;
            u16x8_t v = *(const u16x8_t*)(wq + (size_t)t * (C_ * C_) +
                                          (size_t)(o0 + row) * C_ + kc * BK + seg * 8);
            *(u16x8_t*)&sW[t][row][seg * 8] = v;
        }
        if (SRC == 0) {
            constexpr int NCH = NCOLS * 4;
            for (int e = tid; e < NCH; e += 256) {
                int col = e >> 2, seg = e & 3;
                int gl = l0 - DIL + col;
                u16x8_t v = {0, 0, 0, 0, 0, 0, 0, 0};
                if (gl >= 0 && gl < L_)
                    v = *(const u16x8_t*)((const unsigned short*)xin +
                        (((size_t)bb * 16 + kc) * L_ + gl) * 32 + seg * 8);
                *(u16x8_t*)&sX[col][seg * 8] = v;
            }
        } else {
            constexpr int NE = NCOLS * BK;
            for (int e = tid; e < NE; e += 256) {
                int row = e / NCOLS;
                int col = e - row * NCOLS;
                int gl = l0 - DIL + col;
                unsigned short bits = 0;
                if (gl >= 0 && gl < L_)
                    bits = f2bf(((const float*)xin)[((size_t)bb * C_ + kc * BK + row) * L_ + gl]);
                sX[col][row] = bits;
            }
        }
        __syncthreads();
        #pragma unroll
        for (int t = 0; t < KW; ++t) {
            v8bf af[4], bfr[4];
            #pragma unroll
            for (int mi = 0; mi < 4; ++mi)
                af[mi] = __builtin_bit_cast(v8bf,
                    *(const u16x8_t*)&sW[t][wm * 64 + mi * 16 + l15][quad * 8]);
            #pragma unroll
            for (int ni = 0; ni < 4; ++ni)
                bfr[ni] = __builtin_bit_cast(v8bf,
                    *(const u16x8_t*)&sX[wn * 64 + ni * 16 + l15 + t * DIL][quad * 8]);
            #pragma unroll
            for (int mi = 0; mi < 4; ++mi)
                #pragma unroll
                for (int ni = 0; ni < 4; ++ni)
                    acc[mi][ni] = __builtin_amdgcn_mfma_f32_16x16x32_bf16(
                        af[mi], bfr[ni], acc[mi][ni], 0, 0, 0);
        }
    }
    float scl = sums[tidx] * (1.0f / (float)WN) + 1e-5f;
    #pragma unroll
    for (int mi = 0; mi < 4; ++mi) {
        int mb = o0 + wm * 64 + mi * 16 + quad * 4;
        int g  = mb >> 5;
        int j  = mb & 31;
        #pragma unroll
        for (int ni = 0; ni < 4; ++ni) {
            int n = l0 + wn * 64 + ni * 16 + l15;
            if (RES == 0) {
                u16x4_t pk;
                #pragma unroll
                for (int r = 0; r < 4; ++r) {
                    float v = acc[mi][ni][r] * scl + bias[mb + r];
                    v = (v >= 0.f) ? v : 0.1f * v;
                    pk[r] = f2bf(v);
                }
                *(u16x4_t*)((unsigned short*)out +
                    (((size_t)bb * 16 + g) * L_ + n) * 32 + j) = pk;
            } else {
                #pragma unroll
                for (int r = 0; r < 4; ++r) {
                    float* p = (float*)resbuf + ((size_t)bb * C_ + mb + r) * L_ + n;
                    *p = *p + acc[mi][ni][r] * scl + bias[mb + r];
                }
            }
        }
    }
}

extern "C" void kernel_launch(void* const* d_in, const int* in_sizes, int n_in,
                              void* d_out, int out_size, void* d_ws, size_t ws_size,
                              hipStream_t stream) {
    const float* x = (const float*)d_in[0];
    const float* w[6];
    const float* bs[6];
    for (int i = 0; i < 6; ++i) {
        w[i]  = (const float*)d_in[1 + 2 * i];
        bs[i] = (const float*)d_in[2 + 2 * i];
    }
    char* ws = (char*)d_ws;
    float* sums = (float*)ws;
    unsigned short* wqb = (unsigned short*)(ws + 64);
    const size_t HB = (size_t)BATCH * C_ * L_ * 2;              // 67108864 B
    const size_t need_fast = 64 + (size_t)6 * WN * 2 + 2 * HB;  // same as round 2 (fit-proven)
    const bool fast = ws_size >= need_fast;
    unsigned short* xT = (unsigned short*)(ws + 64 + (size_t)6 * WN * 2);
    unsigned short* hT = fast ? (unsigned short*)((char*)xT + HB) : xT;
    float* outf = (float*)d_out;

    hipMemsetAsync(d_ws, 0, 64, stream);
    abssum_kernel<<<dim3(256, 1, 6), 256, 0, stream>>>(w[0], w[1], w[2], w[3], w[4], w[5], sums);
    quantize_kernel<<<dim3(WN / 256, 1, 6), 256, 0, stream>>>(w[0], w[1], w[2], w[3], w[4], w[5],
                                                              sums, wqb);
    dim3 grid(L_ / BN, C_ / BM, BATCH);
    if (fast) {
        transpose_kernel<<<dim3(L_ / 128, 16, BATCH), 256, 0, stream>>>(x, xT);
        for (int i = 0; i < 3; ++i) {
            const unsigned short* wq1 = wqb + (size_t)(2 * i) * WN;
            const unsigned short* wq2 = wqb + (size_t)(2 * i + 1) * WN;
            if (i == 0)      conv_fast<1, 0><<<grid, 256, 0, stream>>>(xT, wq1, sums, 0, bs[0], nullptr, hT);
            else if (i == 1) conv_fast<3, 0><<<grid, 256, 0, stream>>>(xT, wq1, sums, 2, bs[2], nullptr, hT);
            else             conv_fast<5, 0><<<grid, 256, 0, stream>>>(xT, wq1, sums, 4, bs[4], nullptr, hT);
            if (i < 2)
                conv_fast<1, 1><<<grid, 256, 0, stream>>>(hT, wq2, sums, 2 * i + 1, bs[2 * i + 1],
                                                          xT, nullptr);
            else
                conv_fast<1, 3><<<grid, 256, 0, stream>>>(hT, wq2, sums, 2 * i + 1, bs[2 * i + 1],
                                                          xT, outf);
        }
    } else {
        hipMemcpyAsync(d_out, x, (size_t)BATCH * C_ * L_ * 4, hipMemcpyDeviceToDevice, stream);
        for (int i = 0; i < 3; ++i) {
            const unsigned short* wq1 = wqb + (size_t)(2 * i) * WN;
            const unsigned short* wq2 = wqb + (size_t)(2 * i + 1) * WN;
            if (i == 0)      conv_fb<1, 1, 0><<<grid, 256, 0, stream>>>(outf, wq1, sums, 0, bs[0], nullptr, hT);
            else if (i == 1) conv_fb<1, 3, 0><<<grid, 256, 0, stream>>>(outf, wq1, sums, 2, bs[2], nullptr, hT);
            else             conv_fb<1, 5, 0><<<grid, 256, 0, stream>>>(outf, wq1, sums, 4, bs[4], nullptr, hT);
            conv_fb<0, 1, 1><<<grid, 256, 0, stream>>>(hT, wq2, sums, 2 * i + 1, bs[2 * i + 1],
                                                       outf, nullptr);
        }
    }
}